// Round 6
// baseline (1228.823 us; speedup 1.0000x reference)
//
#include <hip/hip_runtime.h>

// SOM BMU one-hot via split-bf16 MFMA GEMM. R6 structure:
//   som_prep : w -> w3 (bf16 [wh|wl|wh] PRE-SWIZZLED into MFMA B-frag order)
//              + wT (f32 transposed, for pass2) + exact wsq
//   som_main : MFMA GEMM + argmin + fused nontemporal one-hot write
//   som_pass2: fp64 re-solve of flagged rows (coalesced via wT), patches out
//
// R5 post-mortem: B loads were uncoalesced (lane stride 768 B -> 64 line
// transactions per dwordx4). 12.2 waves/CU * 64 tiles * 12 * 64 = 600k cyc/CU
// = 250 us, matching the 333 us runtime. R6 pre-swizzles B so every b-load is
// one coalesced 1 KB transaction; same fix (wT) for pass2.

typedef __attribute__((ext_vector_type(8))) short bf16x8;   // 8 bf16 = 4 VGPR
typedef __attribute__((ext_vector_type(4))) float f32x4;

#define SOM_K 1024
#define SOM_D 128
#define MARGIN 0.08f
#define FLAG_CAP 8192

// d_ws layout (bytes):
#define WS_WSQ   64        // 1024 f32                    (4 KB)
#define WS_W3    8192      // 64 tiles x 12 slots x 64 lanes x 8 bf16 (768 KB)
#define WS_FLAGS 794624    // 8192 int                    (32 KB)
#define WS_WT    827392    // wT[128][1024] f32           (512 KB) -> ends 1.35 MB

static __device__ __forceinline__ unsigned short f2bf(float f) {
    unsigned u = __float_as_uint(f);
    return (unsigned short)((u + 0x7FFFu + ((u >> 16) & 1u)) >> 16);  // RNE
}
static __device__ __forceinline__ float bf2f(unsigned short h) {
    return __uint_as_float(((unsigned)h) << 16);
}

// swizzled destination for (proto n, inner index kk) in w3:
//   s = kk>>5 (slot 0..11), q = (kk>>3)&3, j = kk&7, nt = n>>4, c = n&15
//   elem = ((nt*12 + s)*64 + q*16 + c)*8 + j
static __device__ __forceinline__ int w3_idx(int n, int kk) {
    const int s = kk >> 5, q = (kk >> 3) & 3, j = kk & 7;
    return (((n >> 4) * 12 + s) * 64 + q * 16 + (n & 15)) * 8 + j;
}

// ---- prep: w -> w3 (swizzled split-bf16) + wT (transpose) + exact wsq -----
__global__ __launch_bounds__(64) void som_prep(
    const float* __restrict__ w, unsigned short* __restrict__ w3,
    float* __restrict__ wT, float* __restrict__ wsq)
{
    const int n = blockIdx.x;          // proto 0..1023
    const int d = threadIdx.x;         // 0..63
    float v0 = w[n * SOM_D + d];
    float v1 = w[n * SOM_D + 64 + d];
    unsigned short h0 = f2bf(v0), h1 = f2bf(v1);
    unsigned short l0 = f2bf(v0 - bf2f(h0)), l1 = f2bf(v1 - bf2f(h1));
    w3[w3_idx(n, d)]       = h0;   // wh
    w3[w3_idx(n, 64 + d)]  = h1;
    w3[w3_idx(n, 128 + d)] = l0;   // wl
    w3[w3_idx(n, 192 + d)] = l1;
    w3[w3_idx(n, 256 + d)] = h0;   // wh again (pairs with xl)
    w3[w3_idx(n, 320 + d)] = h1;
    wT[d * SOM_K + n]        = v0; // transpose for pass2
    wT[(64 + d) * SOM_K + n] = v1;
    double s = (double)v0 * v0 + (double)v1 * v1;
    #pragma unroll
    for (int off = 32; off > 0; off >>= 1) s += __shfl_down(s, off);
    if (d == 0) wsq[n] = (float)s;
}

// ---- main: MFMA GEMM + argmin + fused one-hot write -----------------------
__global__ __launch_bounds__(64, 2) void som_main(
    const float* __restrict__ x,
    const unsigned short* __restrict__ w3,
    const float* __restrict__ wsq,
    float* __restrict__ out,
    int* __restrict__ flag_count,
    int* __restrict__ flag_list)
{
    const int lane = threadIdx.x;
    const int c = lane & 15;
    const int q = lane >> 4;
    const int R0 = blockIdx.x * 32;          // 3125 * 32 = 100000 exact

    // a-frags: A[m=lane&15][k=8q+j], two 16-row groups, hi+lo (64 VGPR).
    bf16x8 ah[2][4], al[2][4];
    #pragma unroll
    for (int g = 0; g < 2; ++g) {
        const float* xp = x + (size_t)(R0 + 16 * g + c) * SOM_D + 8 * q;
        #pragma unroll
        for (int s = 0; s < 4; ++s) {
            float4 v0 = *(const float4*)(xp + 32 * s);
            float4 v1 = *(const float4*)(xp + 32 * s + 4);
            float xv[8] = {v0.x, v0.y, v0.z, v0.w, v1.x, v1.y, v1.z, v1.w};
            bf16x8 hh, ll;
            #pragma unroll
            for (int j = 0; j < 8; ++j) {
                unsigned short h = f2bf(xv[j]);
                hh[j] = (short)h;
                ll[j] = (short)f2bf(xv[j] - bf2f(h));
            }
            ah[g][s] = hh; al[g][s] = ll;
        }
    }

    float best[2][4], sec[2][4];
    int bk[2][4];
    #pragma unroll
    for (int g = 0; g < 2; ++g)
        #pragma unroll
        for (int r = 0; r < 4; ++r) { best[g][r] = 1e30f; sec[g][r] = 1e30f; bk[g][r] = 0; }

    // coalesced b-frag base: lane*16B; slot stride 1 KB; tile stride 12 KB
    const unsigned short* wbase = w3 + lane * 8;

    auto compute_tile = [&](int n0, const bf16x8* b, float wq) {
        f32x4 a0 = {0.f, 0.f, 0.f, 0.f}, a1 = {0.f, 0.f, 0.f, 0.f};
        #pragma unroll
        for (int s = 0; s < 4; ++s) {   // xh * wh
            a0 = __builtin_amdgcn_mfma_f32_16x16x32_bf16(ah[0][s], b[s], a0, 0, 0, 0);
            a1 = __builtin_amdgcn_mfma_f32_16x16x32_bf16(ah[1][s], b[s], a1, 0, 0, 0);
        }
        #pragma unroll
        for (int s = 0; s < 4; ++s) {   // xh * wl
            a0 = __builtin_amdgcn_mfma_f32_16x16x32_bf16(ah[0][s], b[4 + s], a0, 0, 0, 0);
            a1 = __builtin_amdgcn_mfma_f32_16x16x32_bf16(ah[1][s], b[4 + s], a1, 0, 0, 0);
        }
        #pragma unroll
        for (int s = 0; s < 4; ++s) {   // xl * wh
            a0 = __builtin_amdgcn_mfma_f32_16x16x32_bf16(al[0][s], b[8 + s], a0, 0, 0, 0);
            a1 = __builtin_amdgcn_mfma_f32_16x16x32_bf16(al[1][s], b[8 + s], a1, 0, 0, 0);
        }
        #pragma unroll
        for (int r = 0; r < 4; ++r) {
            float s0 = wq - 2.f * a0[r];
            if (s0 < best[0][r]) { sec[0][r] = best[0][r]; best[0][r] = s0; bk[0][r] = n0 + c; }
            else if (s0 < sec[0][r]) sec[0][r] = s0;
            float s1 = wq - 2.f * a1[r];
            if (s1 < best[1][r]) { sec[1][r] = best[1][r]; best[1][r] = s1; bk[1][r] = n0 + c; }
            else if (s1 < sec[1][r]) sec[1][r] = s1;
        }
    };

    bf16x8 b0[12], b1[12];
    float wq0, wq1;
    {   // tile 0 -> b0
        #pragma unroll
        for (int s = 0; s < 12; ++s) b0[s] = *(const bf16x8*)(wbase + 512 * s);
        wq0 = wsq[c];
    }

    #pragma unroll 1
    for (int it = 0; it < 32; ++it) {
        const int ntA = 2 * it, ntB = 2 * it + 1;
        {   // prefetch ntB -> b1
            const unsigned short* wp = wbase + (size_t)ntB * 12 * 512;
            #pragma unroll
            for (int s = 0; s < 12; ++s) b1[s] = *(const bf16x8*)(wp + 512 * s);
            wq1 = wsq[ntB * 16 + c];
        }
        compute_tile(ntA * 16, b0, wq0);
        if (it < 31) {   // prefetch ntA+2 -> b0
            const unsigned short* wp = wbase + (size_t)(ntA + 2) * 12 * 512;
            #pragma unroll
            for (int s = 0; s < 12; ++s) b0[s] = *(const bf16x8*)(wp + 512 * s);
            wq0 = wsq[(ntA + 2) * 16 + c];
        }
        compute_tile(ntB * 16, b1, wq1);
    }

    // reduce (best, sec, bk) across the 16 c-lanes of each quad-group;
    // xor-butterfly leaves the result in ALL lanes of the group.
    #pragma unroll
    for (int g = 0; g < 2; ++g) {
        #pragma unroll
        for (int r = 0; r < 4; ++r) {
            float b0v = best[g][r], s0v = sec[g][r];
            int k0 = bk[g][r];
            #pragma unroll
            for (int m = 1; m < 16; m <<= 1) {
                float ob = __shfl_xor(b0v, m);
                float os = __shfl_xor(s0v, m);
                int   ok = __shfl_xor(k0, m);
                if (ob < b0v || (ob == b0v && ok < k0)) {
                    s0v = fminf(b0v, os); b0v = ob; k0 = ok;
                } else {
                    s0v = fminf(s0v, ob);
                }
            }
            best[g][r] = b0v; sec[g][r] = s0v; bk[g][r] = k0;
        }
    }

    if (c == 0) {   // lanes 0,16,32,48 hold rows g*16 + 4q + r
        #pragma unroll
        for (int g = 0; g < 2; ++g) {
            #pragma unroll
            for (int r = 0; r < 4; ++r) {
                if (sec[g][r] - best[g][r] < MARGIN) {
                    int i = atomicAdd(flag_count, 1);
                    if (i < FLAG_CAP) flag_list[i] = R0 + g * 16 + 4 * q + r;
                }
            }
        }
    }

    // fused one-hot write: row rr's bmu lives in quad (rr>>2)&3, reg rr&3
    #pragma unroll 1
    for (int rr = 0; rr < 32; ++rr) {
        const int g = rr >> 4, qq = (rr >> 2) & 3, r = rr & 3;
        const int b = __shfl(bk[g][r], qq << 4);
        f32x4* op = (f32x4*)(out + (size_t)(R0 + rr) * SOM_K);
        #pragma unroll
        for (int j = 0; j < 4; ++j) {
            const int e = j * 64 + lane;
            f32x4 v = {0.f, 0.f, 0.f, 0.f};
            if ((b >> 2) == e) v[b & 3] = 1.0f;
            __builtin_nontemporal_store(v, op + e);
        }
    }
}

// ---- pass2: exact fp64 re-solve of flagged rows, coalesced via wT ---------
__global__ __launch_bounds__(64) void som_pass2(
    const float* __restrict__ x,
    const float* __restrict__ wT,      // [d][k] transposed
    float* __restrict__ out,
    const int* __restrict__ flag_count,
    const int* __restrict__ flag_list)
{
    __shared__ float xs[SOM_D];
    const int t = threadIdx.x;
    int cnt = *flag_count;
    if (cnt > FLAG_CAP) cnt = FLAG_CAP;

    for (int i = blockIdx.x; i < cnt; i += gridDim.x) {
        const int row = flag_list[i];
        __syncthreads();   // xs reuse guard
        xs[t]      = x[(size_t)row * SOM_D + t];
        xs[t + 64] = x[(size_t)row * SOM_D + t + 64];
        __syncthreads();

        double best = 1.0e300;
        int bk = 0;
        // lane t owns k = kk*64 + t -> wT reads are lane-consecutive
        #pragma unroll 1
        for (int kk = 0; kk < 16; ++kk) {
            const int k = kk * 64 + t;
            double s0 = 0.0, s1 = 0.0;
            #pragma unroll
            for (int d = 0; d < SOM_D; d += 2) {
                double w0 = (double)wT[d * SOM_K + k],       x0 = (double)xs[d];
                double w1 = (double)wT[(d + 1) * SOM_K + k], x1 = (double)xs[d + 1];
                s0 += w0 * (w0 - 2.0 * x0);
                s1 += w1 * (w1 - 2.0 * x1);
            }
            double s = s0 + s1;
            if (s < best) { best = s; bk = k; }   // within-lane: k ascending
        }
        // wave argmin reduce, tie -> smaller k (np.argmin first-min)
        #pragma unroll
        for (int off = 32; off > 0; off >>= 1) {
            double ob  = __shfl_down(best, off);
            int    obk = __shfl_down(bk, off);
            if (ob < best || (ob == best && obk < bk)) { best = ob; bk = obk; }
        }
        bk = __shfl(bk, 0);

        // rewrite the row
        f32x4* op = (f32x4*)(out + (size_t)row * SOM_K);
        #pragma unroll
        for (int j = 0; j < 4; ++j) {
            const int e = j * 64 + t;
            f32x4 v = {0.f, 0.f, 0.f, 0.f};
            if ((bk >> 2) == e) v[bk & 3] = 1.0f;
            op[e] = v;
        }
    }
}

extern "C" void kernel_launch(void* const* d_in, const int* in_sizes, int n_in,
                              void* d_out, int out_size, void* d_ws, size_t ws_size,
                              hipStream_t stream) {
    const float* x = (const float*)d_in[0];
    const float* w = (const float*)d_in[1];
    float* out = (float*)d_out;

    char* ws = (char*)d_ws;
    int*            flag_count = (int*)ws;
    float*          wsq        = (float*)(ws + WS_WSQ);
    unsigned short* w3         = (unsigned short*)(ws + WS_W3);
    int*            flag_list  = (int*)(ws + WS_FLAGS);
    float*          wT         = (float*)(ws + WS_WT);

    (void)hipMemsetAsync(d_ws, 0, 64, stream);   // flag counter

    som_prep<<<SOM_K, 64, 0, stream>>>(w, w3, wT, wsq);
    som_main<<<3125, 64, 0, stream>>>(x, w3, wsq, out, flag_count, flag_list);
    som_pass2<<<1024, 64, 0, stream>>>(x, wT, out, flag_count, flag_list);
}

// Round 7
// 723.698 us; speedup vs baseline: 1.6980x; 1.6980x over previous
//
#include <hip/hip_runtime.h>

// SOM BMU one-hot via split-bf16 MFMA GEMM. R7 structure:
//   som_prep : 64 blocks, LDS-staged, coalesced w3 (swizzled B-frags) + wsq
//   som_main : MFMA GEMM + argmin + fused nontemporal one-hot write (as R6)
//   som_pass2: fp64 re-solve, ONE 1024-thread BLOCK PER FLAGGED ROW
//              (thread=proto, per-lane contiguous w streams, 16 waves of
//              latency hiding) -- replaces R6's 1-wave-per-row rescan that
//              ran at ~350 us/row (serialized strided loads, Occ 8.9%).
//   MARGIN 0.08 -> 0.04 (~40x the ~1e-3 split-bf16 error bound) halves flags.

typedef __attribute__((ext_vector_type(8))) short bf16x8;   // 8 bf16 = 4 VGPR
typedef __attribute__((ext_vector_type(4))) float f32x4;

#define SOM_K 1024
#define SOM_D 128
#define MARGIN 0.04f
#define FLAG_CAP 8192

// d_ws layout (bytes):
#define WS_WSQ   64        // 1024 f32  (4 KB)
#define WS_W3    8192      // 64 tiles x 12 slots x 64 lanes x 8 bf16 (768 KB)
#define WS_FLAGS 794624    // 8192 int  (32 KB) -> ends ~827 KB

static __device__ __forceinline__ unsigned short f2bf(float f) {
    unsigned u = __float_as_uint(f);
    return (unsigned short)((u + 0x7FFFu + ((u >> 16) & 1u)) >> 16);  // RNE
}
static __device__ __forceinline__ float bf2f(unsigned short h) {
    return __uint_as_float(((unsigned)h) << 16);
}

// ---- prep: w -> w3 (swizzled split-bf16), coalesced; + exact wsq ----------
// w3 element for (proto n, inner kk in [0,384)): with s=kk>>5, q=(kk>>3)&3,
// j=kk&7, nt=n>>4, c=n&15:  flat = ((nt*12+s)*64 + q*16 + c)*8 + j.
// Inner vector is [wh(0..127) | wl(0..127) | wh(0..127)].
__global__ __launch_bounds__(256) void som_prep(
    const float* __restrict__ w, unsigned short* __restrict__ w3,
    float* __restrict__ wsq)
{
    __shared__ float ws_[16][SOM_D];     // 8 KB staging for 16 protos
    const int nt = blockIdx.x;           // tile 0..63
    const int tid = threadIdx.x;

    // coalesced stage: 16 protos x 128 f32 = 2048 elements, 8 rounds
    const float* src = w + (size_t)nt * 16 * SOM_D;
    #pragma unroll
    for (int r = 0; r < 8; ++r) {
        const int e = r * 256 + tid;
        ws_[e >> 7][e & 127] = src[e];
    }
    __syncthreads();

    // coalesced w3 writes: out group G = tid + 256*r (768 groups of 8 shorts)
    unsigned short* dst = w3 + (size_t)nt * 6144;
    #pragma unroll
    for (int r = 0; r < 3; ++r) {
        const int G = r * 256 + tid;     // 0..767
        const int s = G >> 6;            // slot 0..11
        const int l = G & 63;            // lane
        const int c = l & 15, q = l >> 4;
        bf16x8 v;
        #pragma unroll
        for (int j = 0; j < 8; ++j) {
            const int kk = 32 * s + 8 * q + j;       // 0..383
            const int d = kk & 127;
            const float f = ws_[c][d];
            const unsigned short h = f2bf(f);
            v[j] = (short)((kk & 128) ? f2bf(f - bf2f(h)) : h);  // wl : wh
        }
        *(bf16x8*)(dst + G * 8) = v;
    }

    // wsq: threads 0..15 each reduce one proto in fp64 (64 blocks, cheap)
    if (tid < 16) {
        double s = 0.0;
        #pragma unroll 16
        for (int d = 0; d < SOM_D; ++d) {
            double v = (double)ws_[tid][d];
            s += v * v;
        }
        wsq[nt * 16 + tid] = (float)s;
    }
}

// ---- main: MFMA GEMM + argmin + fused one-hot write (unchanged from R6) ---
__global__ __launch_bounds__(64, 2) void som_main(
    const float* __restrict__ x,
    const unsigned short* __restrict__ w3,
    const float* __restrict__ wsq,
    float* __restrict__ out,
    int* __restrict__ flag_count,
    int* __restrict__ flag_list)
{
    const int lane = threadIdx.x;
    const int c = lane & 15;
    const int q = lane >> 4;
    const int R0 = blockIdx.x * 32;          // 3125 * 32 = 100000 exact

    // a-frags: A[m=lane&15][k=8q+j], two 16-row groups, hi+lo (64 VGPR).
    bf16x8 ah[2][4], al[2][4];
    #pragma unroll
    for (int g = 0; g < 2; ++g) {
        const float* xp = x + (size_t)(R0 + 16 * g + c) * SOM_D + 8 * q;
        #pragma unroll
        for (int s = 0; s < 4; ++s) {
            float4 v0 = *(const float4*)(xp + 32 * s);
            float4 v1 = *(const float4*)(xp + 32 * s + 4);
            float xv[8] = {v0.x, v0.y, v0.z, v0.w, v1.x, v1.y, v1.z, v1.w};
            bf16x8 hh, ll;
            #pragma unroll
            for (int j = 0; j < 8; ++j) {
                unsigned short h = f2bf(xv[j]);
                hh[j] = (short)h;
                ll[j] = (short)f2bf(xv[j] - bf2f(h));
            }
            ah[g][s] = hh; al[g][s] = ll;
        }
    }

    float best[2][4], sec[2][4];
    int bk[2][4];
    #pragma unroll
    for (int g = 0; g < 2; ++g)
        #pragma unroll
        for (int r = 0; r < 4; ++r) { best[g][r] = 1e30f; sec[g][r] = 1e30f; bk[g][r] = 0; }

    // coalesced b-frag base: lane*16B; slot stride 1 KB; tile stride 12 KB
    const unsigned short* wbase = w3 + lane * 8;

    auto compute_tile = [&](int n0, const bf16x8* b, float wq) {
        f32x4 a0 = {0.f, 0.f, 0.f, 0.f}, a1 = {0.f, 0.f, 0.f, 0.f};
        #pragma unroll
        for (int s = 0; s < 4; ++s) {   // xh * wh
            a0 = __builtin_amdgcn_mfma_f32_16x16x32_bf16(ah[0][s], b[s], a0, 0, 0, 0);
            a1 = __builtin_amdgcn_mfma_f32_16x16x32_bf16(ah[1][s], b[s], a1, 0, 0, 0);
        }
        #pragma unroll
        for (int s = 0; s < 4; ++s) {   // xh * wl
            a0 = __builtin_amdgcn_mfma_f32_16x16x32_bf16(ah[0][s], b[4 + s], a0, 0, 0, 0);
            a1 = __builtin_amdgcn_mfma_f32_16x16x32_bf16(ah[1][s], b[4 + s], a1, 0, 0, 0);
        }
        #pragma unroll
        for (int s = 0; s < 4; ++s) {   // xl * wh
            a0 = __builtin_amdgcn_mfma_f32_16x16x32_bf16(al[0][s], b[8 + s], a0, 0, 0, 0);
            a1 = __builtin_amdgcn_mfma_f32_16x16x32_bf16(al[1][s], b[8 + s], a1, 0, 0, 0);
        }
        #pragma unroll
        for (int r = 0; r < 4; ++r) {
            float s0 = wq - 2.f * a0[r];
            if (s0 < best[0][r]) { sec[0][r] = best[0][r]; best[0][r] = s0; bk[0][r] = n0 + c; }
            else if (s0 < sec[0][r]) sec[0][r] = s0;
            float s1 = wq - 2.f * a1[r];
            if (s1 < best[1][r]) { sec[1][r] = best[1][r]; best[1][r] = s1; bk[1][r] = n0 + c; }
            else if (s1 < sec[1][r]) sec[1][r] = s1;
        }
    };

    bf16x8 b0[12], b1[12];
    float wq0, wq1;
    {   // tile 0 -> b0
        #pragma unroll
        for (int s = 0; s < 12; ++s) b0[s] = *(const bf16x8*)(wbase + 512 * s);
        wq0 = wsq[c];
    }

    #pragma unroll 1
    for (int it = 0; it < 32; ++it) {
        const int ntA = 2 * it, ntB = 2 * it + 1;
        {   // prefetch ntB -> b1
            const unsigned short* wp = wbase + (size_t)ntB * 12 * 512;
            #pragma unroll
            for (int s = 0; s < 12; ++s) b1[s] = *(const bf16x8*)(wp + 512 * s);
            wq1 = wsq[ntB * 16 + c];
        }
        compute_tile(ntA * 16, b0, wq0);
        if (it < 31) {   // prefetch ntA+2 -> b0
            const unsigned short* wp = wbase + (size_t)(ntA + 2) * 12 * 512;
            #pragma unroll
            for (int s = 0; s < 12; ++s) b0[s] = *(const bf16x8*)(wp + 512 * s);
            wq0 = wsq[(ntA + 2) * 16 + c];
        }
        compute_tile(ntB * 16, b1, wq1);
    }

    // reduce across the 16 c-lanes of each quad-group (result in all lanes)
    #pragma unroll
    for (int g = 0; g < 2; ++g) {
        #pragma unroll
        for (int r = 0; r < 4; ++r) {
            float b0v = best[g][r], s0v = sec[g][r];
            int k0 = bk[g][r];
            #pragma unroll
            for (int m = 1; m < 16; m <<= 1) {
                float ob = __shfl_xor(b0v, m);
                float os = __shfl_xor(s0v, m);
                int   ok = __shfl_xor(k0, m);
                if (ob < b0v || (ob == b0v && ok < k0)) {
                    s0v = fminf(b0v, os); b0v = ob; k0 = ok;
                } else {
                    s0v = fminf(s0v, ob);
                }
            }
            best[g][r] = b0v; sec[g][r] = s0v; bk[g][r] = k0;
        }
    }

    if (c == 0) {   // lanes 0,16,32,48 hold rows g*16 + 4q + r
        #pragma unroll
        for (int g = 0; g < 2; ++g) {
            #pragma unroll
            for (int r = 0; r < 4; ++r) {
                if (sec[g][r] - best[g][r] < MARGIN) {
                    int i = atomicAdd(flag_count, 1);
                    if (i < FLAG_CAP) flag_list[i] = R0 + g * 16 + 4 * q + r;
                }
            }
        }
    }

    // fused one-hot write: row rr's bmu lives in quad (rr>>2)&3, reg rr&3
    #pragma unroll 1
    for (int rr = 0; rr < 32; ++rr) {
        const int g = rr >> 4, qq = (rr >> 2) & 3, r = rr & 3;
        const int b = __shfl(bk[g][r], qq << 4);
        f32x4* op = (f32x4*)(out + (size_t)(R0 + rr) * SOM_K);
        #pragma unroll
        for (int j = 0; j < 4; ++j) {
            const int e = j * 64 + lane;
            f32x4 v = {0.f, 0.f, 0.f, 0.f};
            if ((b >> 2) == e) v[b & 3] = 1.0f;
            __builtin_nontemporal_store(v, op + e);
        }
    }
}

// ---- pass2: fp64 re-solve, one 1024-thread block per flagged row ----------
__global__ __launch_bounds__(1024) void som_pass2(
    const float* __restrict__ x,
    const float* __restrict__ w,
    float* __restrict__ out,
    const int* __restrict__ flag_count,
    const int* __restrict__ flag_list)
{
    __shared__ float xs[SOM_D];
    __shared__ double rbest[16];
    __shared__ int    rk[16];

    const int tid  = threadIdx.x;          // == proto k
    const int lane = tid & 63;
    const int wv   = tid >> 6;             // wave 0..15
    int cnt = *flag_count;
    if (cnt > FLAG_CAP) cnt = FLAG_CAP;

    for (int i = blockIdx.x; i < cnt; i += gridDim.x) {
        const int row = flag_list[i];
        __syncthreads();                   // guard xs/red reuse
        if (tid < SOM_D) xs[tid] = x[(size_t)row * SOM_D + tid];
        __syncthreads();

        // exact fp64 score for proto k = tid (contiguous per-lane w stream)
        const float* wk = w + (size_t)tid * SOM_D;
        double s0 = 0.0, s1 = 0.0;
        #pragma unroll
        for (int d = 0; d < SOM_D; d += 4) {
            float4 wv4 = *(const float4*)(wk + d);
            double w0 = (double)wv4.x, w1 = (double)wv4.y;
            double w2 = (double)wv4.z, w3 = (double)wv4.w;
            s0 += w0 * (w0 - 2.0 * (double)xs[d])     + w2 * (w2 - 2.0 * (double)xs[d + 2]);
            s1 += w1 * (w1 - 2.0 * (double)xs[d + 1]) + w3 * (w3 - 2.0 * (double)xs[d + 3]);
        }
        double sc = s0 + s1;
        int bk = tid;

        // wave argmin (tie -> smaller k)
        #pragma unroll
        for (int off = 32; off > 0; off >>= 1) {
            double os = __shfl_down(sc, off);
            int    ok = __shfl_down(bk, off);
            if (os < sc || (os == sc && ok < bk)) { sc = os; bk = ok; }
        }
        if (lane == 0) { rbest[wv] = sc; rk[wv] = bk; }
        __syncthreads();

        // cross-wave argmin by wave 0, ascending wave order = ascending k
        if (tid == 0) {
            double b = rbest[0]; int k0 = rk[0];
            #pragma unroll
            for (int v = 1; v < 16; ++v) {
                if (rbest[v] < b || (rbest[v] == b && rk[v] < k0)) { b = rbest[v]; k0 = rk[v]; }
            }
            rk[0] = k0;
        }
        __syncthreads();
        const int bmu = rk[0];

        // coalesced row rewrite (full overwrite)
        out[(size_t)row * SOM_K + tid] = (tid == bmu) ? 1.0f : 0.0f;
    }
}

extern "C" void kernel_launch(void* const* d_in, const int* in_sizes, int n_in,
                              void* d_out, int out_size, void* d_ws, size_t ws_size,
                              hipStream_t stream) {
    const float* x = (const float*)d_in[0];
    const float* w = (const float*)d_in[1];
    float* out = (float*)d_out;

    char* ws = (char*)d_ws;
    int*            flag_count = (int*)ws;
    float*          wsq        = (float*)(ws + WS_WSQ);
    unsigned short* w3         = (unsigned short*)(ws + WS_W3);
    int*            flag_list  = (int*)(ws + WS_FLAGS);

    (void)hipMemsetAsync(d_ws, 0, 64, stream);   // flag counter

    som_prep<<<64, 256, 0, stream>>>(w, w3, wsq);
    som_main<<<3125, 64, 0, stream>>>(x, w3, wsq, out, flag_count, flag_list);
    som_pass2<<<1024, 1024, 0, stream>>>(x, w, out, flag_count, flag_list);
}

// Round 8
// 647.296 us; speedup vs baseline: 1.8984x; 1.1180x over previous
//
#include <hip/hip_runtime.h>

// SOM BMU one-hot via split-bf16 MFMA GEMM. R8 structure:
//   som_prep : w -> w3 (8-slot swizzled B-frags: [wh x4 | wl x4], 512 KB) + wsq
//   som_main : MFMA GEMM, 8 B-loads/tile, xl*wh REUSES b[0..3] regs,
//              single-buffered B (VGPR ~150 -> 3 waves/SIMD for TLP),
//              argmin + fused nontemporal one-hot write
//   som_pass2: fp64 re-solve, one 1024-thread block per flagged row
//
// R7 post-mortem: ~256 us of each timed iteration is the harness d_out/d_ws
// poison fill (fillBufferAligned, 1.6 GB @6.4 TB/s) -- untouchable floor.
// Controllable budget was ~468 us; main's L2 stream (2.4 GB) was the biggest
// modeled term. R8: w3 768->512 KB (-33% L2), MARGIN 0.04->0.02 (~280 flags).

typedef __attribute__((ext_vector_type(8))) short bf16x8;   // 8 bf16 = 4 VGPR
typedef __attribute__((ext_vector_type(4))) float f32x4;

#define SOM_K 1024
#define SOM_D 128
#define MARGIN 0.02f
#define FLAG_CAP 8192

// d_ws layout (bytes):
#define WS_WSQ   64        // 1024 f32  (4 KB)
#define WS_W3    8192      // 64 tiles x 8 slots x 64 lanes x 8 bf16 (512 KB)
#define WS_FLAGS 532480    // 8192 int  (32 KB) -> ends ~565 KB

static __device__ __forceinline__ unsigned short f2bf(float f) {
    unsigned u = __float_as_uint(f);
    return (unsigned short)((u + 0x7FFFu + ((u >> 16) & 1u)) >> 16);  // RNE
}
static __device__ __forceinline__ float bf2f(unsigned short h) {
    return __uint_as_float(((unsigned)h) << 16);
}

// ---- prep: w -> w3 (swizzled split-bf16, 8 slots) + exact wsq -------------
// w3 element for (proto n, inner kk in [0,256)): s=kk>>5 (slot), q=(kk>>3)&3,
// j=kk&7, nt=n>>4, c=n&15:  flat = ((nt*8+s)*64 + q*16 + c)*8 + j.
// Inner vector is [wh(dims 0..127) | wl(dims 0..127)].
__global__ __launch_bounds__(256) void som_prep(
    const float* __restrict__ w, unsigned short* __restrict__ w3,
    float* __restrict__ wsq)
{
    __shared__ float ws_[16][SOM_D];     // 8 KB staging for 16 protos
    const int nt = blockIdx.x;           // tile 0..63
    const int tid = threadIdx.x;

    const float* src = w + (size_t)nt * 16 * SOM_D;
    #pragma unroll
    for (int r = 0; r < 8; ++r) {
        const int e = r * 256 + tid;
        ws_[e >> 7][e & 127] = src[e];
    }
    __syncthreads();

    unsigned short* dst = w3 + (size_t)nt * 4096;
    #pragma unroll
    for (int r = 0; r < 2; ++r) {
        const int G = r * 256 + tid;     // 0..511
        const int s = G >> 6;            // slot 0..7
        const int l = G & 63;            // lane
        const int c = l & 15, q = l >> 4;
        bf16x8 v;
        #pragma unroll
        for (int j = 0; j < 8; ++j) {
            const int kk = 32 * s + 8 * q + j;       // 0..255
            const int d = kk & 127;
            const float f = ws_[c][d];
            const unsigned short h = f2bf(f);
            v[j] = (short)((kk & 128) ? f2bf(f - bf2f(h)) : h);  // wl : wh
        }
        *(bf16x8*)(dst + G * 8) = v;
    }

    if (tid < 16) {
        double s = 0.0;
        #pragma unroll 16
        for (int d = 0; d < SOM_D; ++d) {
            double v = (double)ws_[tid][d];
            s += v * v;
        }
        wsq[nt * 16 + tid] = (float)s;
    }
}

// ---- main: MFMA GEMM + argmin + fused one-hot write -----------------------
__global__ __launch_bounds__(64, 2) void som_main(
    const float* __restrict__ x,
    const unsigned short* __restrict__ w3,
    const float* __restrict__ wsq,
    float* __restrict__ out,
    int* __restrict__ flag_count,
    int* __restrict__ flag_list)
{
    const int lane = threadIdx.x;
    const int c = lane & 15;
    const int q = lane >> 4;
    const int R0 = blockIdx.x * 32;          // 3125 * 32 = 100000 exact

    // a-frags: A[m=lane&15][k=8q+j], two 16-row groups, hi+lo (64 VGPR).
    bf16x8 ah[2][4], al[2][4];
    #pragma unroll
    for (int g = 0; g < 2; ++g) {
        const float* xp = x + (size_t)(R0 + 16 * g + c) * SOM_D + 8 * q;
        #pragma unroll
        for (int s = 0; s < 4; ++s) {
            float4 v0 = *(const float4*)(xp + 32 * s);
            float4 v1 = *(const float4*)(xp + 32 * s + 4);
            float xv[8] = {v0.x, v0.y, v0.z, v0.w, v1.x, v1.y, v1.z, v1.w};
            bf16x8 hh, ll;
            #pragma unroll
            for (int j = 0; j < 8; ++j) {
                unsigned short h = f2bf(xv[j]);
                hh[j] = (short)h;
                ll[j] = (short)f2bf(xv[j] - bf2f(h));
            }
            ah[g][s] = hh; al[g][s] = ll;
        }
    }

    float best[2][4], sec[2][4];
    int bk[2][4];
    #pragma unroll
    for (int g = 0; g < 2; ++g)
        #pragma unroll
        for (int r = 0; r < 4; ++r) { best[g][r] = 1e30f; sec[g][r] = 1e30f; bk[g][r] = 0; }

    // coalesced b-frag base: lane*16B; slot stride 1 KB; tile stride 8 KB
    const unsigned short* wbase = w3 + lane * 8;

    #pragma unroll 1
    for (int nt = 0; nt < 64; ++nt) {
        const int n0 = nt * 16;
        const unsigned short* wp = wbase + (size_t)nt * 4096;
        bf16x8 b[8];
        #pragma unroll
        for (int s = 0; s < 8; ++s) b[s] = *(const bf16x8*)(wp + 512 * s);
        const float wq = wsq[n0 + c];

        f32x4 a0 = {0.f, 0.f, 0.f, 0.f}, a1 = {0.f, 0.f, 0.f, 0.f};
        #pragma unroll
        for (int s = 0; s < 4; ++s) {   // xh * wh
            a0 = __builtin_amdgcn_mfma_f32_16x16x32_bf16(ah[0][s], b[s], a0, 0, 0, 0);
            a1 = __builtin_amdgcn_mfma_f32_16x16x32_bf16(ah[1][s], b[s], a1, 0, 0, 0);
        }
        #pragma unroll
        for (int s = 0; s < 4; ++s) {   // xh * wl
            a0 = __builtin_amdgcn_mfma_f32_16x16x32_bf16(ah[0][s], b[4 + s], a0, 0, 0, 0);
            a1 = __builtin_amdgcn_mfma_f32_16x16x32_bf16(ah[1][s], b[4 + s], a1, 0, 0, 0);
        }
        #pragma unroll
        for (int s = 0; s < 4; ++s) {   // xl * wh -- reuses b[0..3]
            a0 = __builtin_amdgcn_mfma_f32_16x16x32_bf16(al[0][s], b[s], a0, 0, 0, 0);
            a1 = __builtin_amdgcn_mfma_f32_16x16x32_bf16(al[1][s], b[s], a1, 0, 0, 0);
        }

        #pragma unroll
        for (int r = 0; r < 4; ++r) {
            float s0 = wq - 2.f * a0[r];
            if (s0 < best[0][r]) { sec[0][r] = best[0][r]; best[0][r] = s0; bk[0][r] = n0 + c; }
            else if (s0 < sec[0][r]) sec[0][r] = s0;
            float s1 = wq - 2.f * a1[r];
            if (s1 < best[1][r]) { sec[1][r] = best[1][r]; best[1][r] = s1; bk[1][r] = n0 + c; }
            else if (s1 < sec[1][r]) sec[1][r] = s1;
        }
    }

    // reduce across the 16 c-lanes of each quad-group (result in all lanes)
    #pragma unroll
    for (int g = 0; g < 2; ++g) {
        #pragma unroll
        for (int r = 0; r < 4; ++r) {
            float b0v = best[g][r], s0v = sec[g][r];
            int k0 = bk[g][r];
            #pragma unroll
            for (int m = 1; m < 16; m <<= 1) {
                float ob = __shfl_xor(b0v, m);
                float os = __shfl_xor(s0v, m);
                int   ok = __shfl_xor(k0, m);
                if (ob < b0v || (ob == b0v && ok < k0)) {
                    s0v = fminf(b0v, os); b0v = ob; k0 = ok;
                } else {
                    s0v = fminf(s0v, ob);
                }
            }
            best[g][r] = b0v; sec[g][r] = s0v; bk[g][r] = k0;
        }
    }

    if (c == 0) {   // lanes 0,16,32,48 hold rows g*16 + 4q + r
        #pragma unroll
        for (int g = 0; g < 2; ++g) {
            #pragma unroll
            for (int r = 0; r < 4; ++r) {
                if (sec[g][r] - best[g][r] < MARGIN) {
                    int i = atomicAdd(flag_count, 1);
                    if (i < FLAG_CAP) flag_list[i] = R0 + g * 16 + 4 * q + r;
                }
            }
        }
    }

    // fused one-hot write: row rr's bmu lives in quad (rr>>2)&3, reg rr&3
    #pragma unroll 1
    for (int rr = 0; rr < 32; ++rr) {
        const int g = rr >> 4, qq = (rr >> 2) & 3, r = rr & 3;
        const int b = __shfl(bk[g][r], qq << 4);
        f32x4* op = (f32x4*)(out + (size_t)(R0 + rr) * SOM_K);
        #pragma unroll
        for (int j = 0; j < 4; ++j) {
            const int e = j * 64 + lane;
            f32x4 v = {0.f, 0.f, 0.f, 0.f};
            if ((b >> 2) == e) v[b & 3] = 1.0f;
            __builtin_nontemporal_store(v, op + e);
        }
    }
}

// ---- pass2: fp64 re-solve, one 1024-thread block per flagged row ----------
__global__ __launch_bounds__(1024) void som_pass2(
    const float* __restrict__ x,
    const float* __restrict__ w,
    float* __restrict__ out,
    const int* __restrict__ flag_count,
    const int* __restrict__ flag_list)
{
    __shared__ float xs[SOM_D];
    __shared__ double rbest[16];
    __shared__ int    rk[16];

    const int tid  = threadIdx.x;          // == proto k
    const int lane = tid & 63;
    const int wv   = tid >> 6;             // wave 0..15
    int cnt = *flag_count;
    if (cnt > FLAG_CAP) cnt = FLAG_CAP;

    for (int i = blockIdx.x; i < cnt; i += gridDim.x) {
        const int row = flag_list[i];
        __syncthreads();                   // guard xs/red reuse
        if (tid < SOM_D) xs[tid] = x[(size_t)row * SOM_D + tid];
        __syncthreads();

        // exact fp64 score for proto k = tid (contiguous per-lane w stream)
        const float* wk = w + (size_t)tid * SOM_D;
        double s0 = 0.0, s1 = 0.0;
        #pragma unroll
        for (int d = 0; d < SOM_D; d += 4) {
            float4 wv4 = *(const float4*)(wk + d);
            double w0 = (double)wv4.x, w1 = (double)wv4.y;
            double w2 = (double)wv4.z, w3 = (double)wv4.w;
            s0 += w0 * (w0 - 2.0 * (double)xs[d])     + w2 * (w2 - 2.0 * (double)xs[d + 2]);
            s1 += w1 * (w1 - 2.0 * (double)xs[d + 1]) + w3 * (w3 - 2.0 * (double)xs[d + 3]);
        }
        double sc = s0 + s1;
        int bk = tid;

        // wave argmin (tie -> smaller k)
        #pragma unroll
        for (int off = 32; off > 0; off >>= 1) {
            double os = __shfl_down(sc, off);
            int    ok = __shfl_down(bk, off);
            if (os < sc || (os == sc && ok < bk)) { sc = os; bk = ok; }
        }
        if (lane == 0) { rbest[wv] = sc; rk[wv] = bk; }
        __syncthreads();

        if (tid == 0) {
            double b = rbest[0]; int k0 = rk[0];
            #pragma unroll
            for (int v = 1; v < 16; ++v) {
                if (rbest[v] < b || (rbest[v] == b && rk[v] < k0)) { b = rbest[v]; k0 = rk[v]; }
            }
            rk[0] = k0;
        }
        __syncthreads();
        const int bmu = rk[0];

        out[(size_t)row * SOM_K + tid] = (tid == bmu) ? 1.0f : 0.0f;
    }
}

extern "C" void kernel_launch(void* const* d_in, const int* in_sizes, int n_in,
                              void* d_out, int out_size, void* d_ws, size_t ws_size,
                              hipStream_t stream) {
    const float* x = (const float*)d_in[0];
    const float* w = (const float*)d_in[1];
    float* out = (float*)d_out;

    char* ws = (char*)d_ws;
    int*            flag_count = (int*)ws;
    float*          wsq        = (float*)(ws + WS_WSQ);
    unsigned short* w3         = (unsigned short*)(ws + WS_W3);
    int*            flag_list  = (int*)(ws + WS_FLAGS);

    (void)hipMemsetAsync(d_ws, 0, 64, stream);   // flag counter

    som_prep<<<64, 256, 0, stream>>>(w, w3, wsq);
    som_main<<<3125, 64, 0, stream>>>(x, w3, wsq, out, flag_count, flag_list);
    som_pass2<<<256, 1024, 0, stream>>>(x, w, out, flag_count, flag_list);
}